// Round 6
// baseline (1034.876 us; speedup 1.0000x reference)
//
#include <hip/hip_runtime.h>
#include <hip/hip_bf16.h>
#include <math.h>

#define K_CODES 8192
#define D_DIM   512
#define N_ROWS  16384
#define DECAYF  0.99f
#define OMDF    0.01f
#define COMMIT  0.25f
#define EPSV    1e-5f

// output offsets (in floats), reference return order:
// z_q_st (8*2048*512), loss (1), indices (8*2048), new_embedding (8192*512),
// ema_cs (8192), ema_es (8192*512)
#define OUT0_OFF 0ull
#define OUT1_OFF 8388608ull
#define OUT2_OFF 8388609ull
#define OUT3_OFF 8404993ull
#define OUT4_OFF 12599297ull
#define OUT5_OFF 12607489ull

#define BM 128
#define BN 256
#define BKC 32
#define NRB (N_ROWS / BM)    // 128 rowblocks
#define NCB (K_CODES / BN)   // 32 colblocks
#define NITER (D_DIM / BKC)  // 16

typedef _Float16 f16x8 __attribute__((ext_vector_type(8)));
typedef float    f32x4 __attribute__((ext_vector_type(4)));
typedef unsigned short u16;

#define GLOAD16(srcp, dstp) __builtin_amdgcn_global_load_lds( \
    (const __attribute__((address_space(1))) unsigned int*)(const void*)(srcp), \
    (__attribute__((address_space(3))) unsigned int*)(void*)(dstp), 16, 0, 0)

// ---------------- exact numpy pairwise sum of squares, wave-parallel ----------------
// numpy pairwise(512) = ((B0+B1)+(B2+B3)), each B = base-128 block:
// r[j] = p[j]; r[j] += p[8i+j] for i=1..15; ((r0+r1)+(r2+r3))+((r4+r5)+(r6+r7)).
// Lane j of an 8-lane group owns r[j]; IEEE RN add is commutative, so the
// shfl_xor tree reproduces numpy's exact pairing.
__global__ void norms_np_kernel(const float* __restrict__ src, float* __restrict__ dst) {
    int lane = threadIdx.x & 63;
    int wave = threadIdx.x >> 6;            // 4 waves/block
    int half = lane >> 5;                   // row within wave (2 rows/wave)
    int l32  = lane & 31;
    int row  = blockIdx.x * 8 + wave * 2 + half;
    int j    = l32 & 7;
    int blk  = l32 >> 3;
    const float* p = src + (size_t)row * D_DIM + blk * 128 + j;
    float x0 = p[0];
    float r = __fmul_rn(x0, x0);
#pragma unroll
    for (int i = 1; i < 16; i++) {
        float x = p[i * 8];
        r = __fadd_rn(r, __fmul_rn(x, x));
    }
    float s1 = __fadd_rn(r,  __shfl_xor(r, 1, 64));
    float s2 = __fadd_rn(s1, __shfl_xor(s1, 2, 64));
    float s4 = __fadd_rn(s2, __shfl_xor(s2, 4, 64));   // B[blk]
    float t1 = __fadd_rn(s4, __shfl_xor(s4, 8, 64));   // B0+B1 | B2+B3
    float t2 = __fadd_rn(t1, __shfl_xor(t1, 16, 64));  // total
    if (l32 == 0) dst[row] = t2;
}

// ---------------- hi/lo fp16 split converters ----------------
__global__ void convert_z_kernel(const float* __restrict__ z,
                                 u16* __restrict__ zhi, u16* __restrict__ zlo) {
    size_t t = (size_t)blockIdx.x * 256 + threadIdx.x;   // 1,048,576 tasks x 8 elems
    const float4* src = (const float4*)z + t * 2;
    float4 v0 = src[0], v1 = src[1];
    float vv[8] = {v0.x, v0.y, v0.z, v0.w, v1.x, v1.y, v1.z, v1.w};
    f16x8 hv, lv;
#pragma unroll
    for (int j = 0; j < 8; j++) {
        _Float16 h = (_Float16)vv[j];
        hv[j] = h;
        lv[j] = (_Float16)(vv[j] - (float)h);
    }
    ((f16x8*)zhi)[t] = hv;
    ((f16x8*)zlo)[t] = lv;
}

__global__ void convert_e_kernel(const float* __restrict__ E,
                                 u16* __restrict__ ehi, u16* __restrict__ elo) {
    size_t t = (size_t)blockIdx.x * 256 + threadIdx.x;   // 524,288 tasks x 8 elems
    const float4* src = (const float4*)E + t * 2;
    float4 v0 = src[0], v1 = src[1];
    float vv[8] = {v0.x, v0.y, v0.z, v0.w, v1.x, v1.y, v1.z, v1.w};
    f16x8 hv, lv;
#pragma unroll
    for (int j = 0; j < 8; j++) {
        float s = vv[j] * 4096.0f;     // exact exponent shift
        _Float16 h = (_Float16)s;
        hv[j] = h;
        lv[j] = (_Float16)(s - (float)h);
    }
    ((f16x8*)ehi)[t] = hv;
    ((f16x8*)elo)[t] = lv;
}

// ---------------- MFMA distance GEMM + argmin (2 blocks/CU, single-buffer) --------
// dist = fl( fl(z2 - acc*2^-11) + e2 ), acc = 3-product split dot * 4096.
// 48 KB LDS single buffer + plain 2-barrier chunk loop; latency hidden by
// cross-block overlap (2 blocks/CU, 16 waves/CU).
__global__ __launch_bounds__(512, 4) void argmin_mfma_kernel(
    const u16* __restrict__ zhi, const u16* __restrict__ zlo,
    const u16* __restrict__ ehi, const u16* __restrict__ elo,
    const float* __restrict__ e2, const float* __restrict__ z2,
    float* __restrict__ pv, int* __restrict__ pi)
{
    __shared__ __align__(16) u16 ldsA[2][512][8];    // [hi/lo][g*128+row][8]  16 KB
    __shared__ __align__(16) u16 ldsB[2][1024][8];   // [hi/lo][g*256+row][8]  32 KB

    int bid = blockIdx.x;
    int xcd = bid & 7, sub = bid >> 3;       // 4096 = 8 XCDs * 512
    int rb  = sub >> 2;                      // rb-major: A rowblock reused across
    int cb  = xcd * 4 + (sub & 3);           //   4 resident B-panels per XCD
    int row0 = rb * BM, col0 = cb * BN;

    int tid = threadIdx.x;
    int l   = tid & 63;
    int w   = tid >> 6;
    int mw  = w >> 2, nw = w & 3;            // wave grid 2(m) x 4(n), 64x64 per wave
    int lg  = l >> 4;                        // k-group 0..3
    int l16 = l & 15;

    f32x4 acc[4][4];
#pragma unroll
    for (int m = 0; m < 4; m++)
#pragma unroll
        for (int n = 0; n < 4; n++)
            acc[m][n] = (f32x4){0.f, 0.f, 0.f, 0.f};

    for (int t = 0; t < NITER; t++) {
        int kb = t * BKC;
        __syncthreads();   // prior chunk's ds_reads complete before overwrite
        {   // stage A: 2 gload/lane; B: 4 gload/lane
            int g = tid >> 7, r = tid & 127;
            size_t offA = (size_t)(row0 + r) * D_DIM + kb + g * 8;
            GLOAD16(zhi + offA, &ldsA[0][tid][0]);
            GLOAD16(zlo + offA, &ldsA[1][tid][0]);
#pragma unroll
            for (int i = 0; i < 2; i++) {
                int slot = tid + i * 512;
                int gb = slot >> 8, rr = slot & 255;
                size_t offB = (size_t)(col0 + rr) * D_DIM + kb + gb * 8;
                GLOAD16(ehi + offB, &ldsB[0][slot][0]);
                GLOAD16(elo + offB, &ldsB[1][slot][0]);
            }
        }
        __syncthreads();   // compiler drains vmcnt before barrier -> tile visible

        f16x8 bh[4], bl[4];
#pragma unroll
        for (int n = 0; n < 4; n++) {
            int s = lg * 256 + nw * 64 + n * 16 + l16;
            bh[n] = *(const f16x8*)&ldsB[0][s][0];
            bl[n] = *(const f16x8*)&ldsB[1][s][0];
        }
#pragma unroll
        for (int m = 0; m < 4; m++) {
            int s = lg * 128 + mw * 64 + m * 16 + l16;
            f16x8 ah = *(const f16x8*)&ldsA[0][s][0];
            f16x8 al = *(const f16x8*)&ldsA[1][s][0];
#pragma unroll
            for (int n = 0; n < 4; n++)
                acc[m][n] = __builtin_amdgcn_mfma_f32_16x16x32_f16(ah, bh[n], acc[m][n], 0, 0, 0);
#pragma unroll
            for (int n = 0; n < 4; n++)
                acc[m][n] = __builtin_amdgcn_mfma_f32_16x16x32_f16(ah, bl[n], acc[m][n], 0, 0, 0);
#pragma unroll
            for (int n = 0; n < 4; n++)
                acc[m][n] = __builtin_amdgcn_mfma_f32_16x16x32_f16(al, bh[n], acc[m][n], 0, 0, 0);
        }
    }

    // ---- epilogue: distances + first-occurrence argmin ----
    const float nscale = -0.00048828125f;   // -2^-11 (undo 4096 scale, apply -2)
    float e2c[4];
#pragma unroll
    for (int n = 0; n < 4; n++) e2c[n] = e2[col0 + nw * 64 + n * 16 + l16];

    __syncthreads();                              // all frag reads done; reuse LDS
    float* redv = (float*)&ldsA[0][0][0];         // [128][4] vals (2 KB)
    int*   redi = (int*)&ldsB[0][0][0];           // [128][4] idx  (2 KB)

#pragma unroll
    for (int m = 0; m < 4; m++) {
#pragma unroll
        for (int r = 0; r < 4; r++) {
            int rl = mw * 64 + m * 16 + lg * 4 + r;
            float z2v = z2[row0 + rl];
            float bv = 1e30f; int bc = 0x7fffffff;
#pragma unroll
            for (int n = 0; n < 4; n++) {
                int code = col0 + nw * 64 + n * 16 + l16;
                float v = __fadd_rn(__fadd_rn(z2v, __fmul_rn(acc[m][n][r], nscale)), e2c[n]);
                if (v < bv) { bv = v; bc = code; }   // n ascending => code ascending
            }
#pragma unroll
            for (int s = 1; s < 16; s <<= 1) {
                float ov = __shfl_xor(bv, s, 64);
                int   oc = __shfl_xor(bc, s, 64);
                if (ov < bv || (ov == bv && oc < bc)) { bv = ov; bc = oc; }
            }
            if (l16 == r) {
                redv[rl * 4 + nw] = bv;
                redi[rl * 4 + nw] = bc;
            }
        }
    }
    __syncthreads();
    if (tid < BM) {
        float bv = redv[tid * 4]; int bc = redi[tid * 4];
#pragma unroll
        for (int q = 1; q < 4; q++) {
            float v = redv[tid * 4 + q]; int c = redi[tid * 4 + q];
            if (v < bv || (v == bv && c < bc)) { bv = v; bc = c; }
        }
        pv[(size_t)cb * N_ROWS + row0 + tid] = bv;
        pi[(size_t)cb * N_ROWS + row0 + tid] = bc;
    }
}

// ---------------- combine colblock partials -> final index ----------------
__global__ void combine_kernel(const float* __restrict__ pv, const int* __restrict__ pi,
                               int* __restrict__ idx_out, float* __restrict__ out2) {
    int row = blockIdx.x * 256 + threadIdx.x;
    float bv = pv[row];
    int   bi = pi[row];
#pragma unroll 4
    for (int cb = 1; cb < NCB; cb++) {
        float v = pv[(size_t)cb * N_ROWS + row];
        int   c = pi[(size_t)cb * N_ROWS + row];
        if (v < bv || (v == bv && c < bi)) { bv = v; bi = c; }
    }
    idx_out[row] = bi;
    out2[row] = (float)bi;
}

// ---------------- gather z_q, loss, segment-sum scatter ----------------
__global__ void gather_kernel(const float* __restrict__ z, const float* __restrict__ E,
                              const int* __restrict__ idx, float* __restrict__ out0,
                              float* __restrict__ out4_acc, float* __restrict__ out5_acc,
                              float* __restrict__ loss_acc) {
    int row = blockIdx.x;
    int t = threadIdx.x;   // 128
    int k = idx[row];
    int d = t * 4;
    float4 zv = *(const float4*)(z + (size_t)row * D_DIM + d);
    float4 qv = *(const float4*)(E + (size_t)k * D_DIM + d);
    float4 o;
    o.x = __fadd_rn(zv.x, __fsub_rn(qv.x, zv.x));
    o.y = __fadd_rn(zv.y, __fsub_rn(qv.y, zv.y));
    o.z = __fadd_rn(zv.z, __fsub_rn(qv.z, zv.z));
    o.w = __fadd_rn(zv.w, __fsub_rn(qv.w, zv.w));
    *(float4*)(out0 + (size_t)row * D_DIM + d) = o;
    float dx = qv.x - zv.x, dy = qv.y - zv.y, dz = qv.z - zv.z, dw = qv.w - zv.w;
    float s = dx * dx + dy * dy + dz * dz + dw * dw;
#pragma unroll
    for (int off = 32; off; off >>= 1) s += __shfl_down(s, off, 64);
    __shared__ float part[2];
    if ((t & 63) == 0) part[t >> 6] = s;
    __syncthreads();
    if (t == 0) atomicAdd(loss_acc, part[0] + part[1]);
    float* dst = out5_acc + (size_t)k * D_DIM + d;
    atomicAdd(dst + 0, OMDF * zv.x);
    atomicAdd(dst + 1, OMDF * zv.y);
    atomicAdd(dst + 2, OMDF * zv.z);
    atomicAdd(dst + 3, OMDF * zv.w);
    if (t == 0) atomicAdd(out4_acc + k, OMDF);
}

// ---------------- sum of input ema_cluster_size ----------------
__global__ void sum_cs_kernel(const float* __restrict__ cs, float* __restrict__ out_sum) {
    int t = threadIdx.x;  // 256
    float s = 0.f;
    for (int i = t; i < K_CODES; i += 256) s += cs[i];
#pragma unroll
    for (int off = 32; off; off >>= 1) s += __shfl_down(s, off, 64);
    __shared__ float part[4];
    if ((t & 63) == 0) part[t >> 6] = s;
    __syncthreads();
    if (t == 0) out_sum[0] = part[0] + part[1] + part[2] + part[3];
}

// ---------------- EMA finalize + smoothing + new embedding ----------------
__global__ void finalize_kernel(const float* __restrict__ in_cs, const float* __restrict__ in_es,
                                float* __restrict__ out1, float* __restrict__ out3,
                                float* __restrict__ out4, float* __restrict__ out5,
                                const float* __restrict__ s_in, const float* __restrict__ loss_acc) {
    int k = blockIdx.x;
    int t = threadIdx.x;  // 128
    float cs_acc = out4[k];                       // 0.01 * count_k (accumulated)
    float ema_cs = DECAYF * in_cs[k] + cs_acc;
    float n = DECAYF * s_in[0] + OMDF * (float)N_ROWS;
    float smoothed = (ema_cs + EPSV) / (n + (float)K_CODES * EPSV) * n;
    int d = t * 4;
    float4 esv = *(const float4*)(in_es + (size_t)k * D_DIM + d);
    float4 accv = *(const float4*)(out5 + (size_t)k * D_DIM + d);
    float4 ema;
    ema.x = DECAYF * esv.x + accv.x;
    ema.y = DECAYF * esv.y + accv.y;
    ema.z = DECAYF * esv.z + accv.z;
    ema.w = DECAYF * esv.w + accv.w;
    *(float4*)(out5 + (size_t)k * D_DIM + d) = ema;
    float4 emb;
    emb.x = ema.x / smoothed;
    emb.y = ema.y / smoothed;
    emb.z = ema.z / smoothed;
    emb.w = ema.w / smoothed;
    *(float4*)(out3 + (size_t)k * D_DIM + d) = emb;
    if (t == 0) out4[k] = ema_cs;
    if (k == 0 && t == 0) out1[0] = COMMIT * loss_acc[0] / (float)(N_ROWS * D_DIM);
}

extern "C" void kernel_launch(void* const* d_in, const int* in_sizes, int n_in,
                              void* d_out, int out_size, void* d_ws, size_t ws_size,
                              hipStream_t stream) {
    const float* z     = (const float*)d_in[0];
    const float* E     = (const float*)d_in[1];
    const float* in_cs = (const float*)d_in[2];
    const float* in_es = (const float*)d_in[3];

    float* out  = (float*)d_out;
    float* out0 = out + OUT0_OFF;
    float* out1 = out + OUT1_OFF;
    float* out2 = out + OUT2_OFF;
    float* out3 = out + OUT3_OFF;
    float* out4 = out + OUT4_OFF;
    float* out5 = out + OUT5_OFF;

    // hi/lo fp16 planes stashed in output regions (overwritten later):
    u16* zhi = (u16*)out0;                                   // 16.78 MB
    u16* zlo = zhi + (size_t)N_ROWS * D_DIM;                 // 16.78 MB (out0 exactly)
    u16* ehi = (u16*)(out + OUT3_OFF + 3);                   // +3 floats => 16B aligned
    u16* elo = ehi + (size_t)K_CODES * D_DIM;                // spills 3 floats into out4 (memset later)
    // argmin partials scratch in out5 region (memset happens after combine):
    float* pv = out5;                                        // 32*16384 floats = 2 MB
    int*   pi = (int*)(out5 + (size_t)NCB * N_ROWS);         // 2 MB

    char* ws = (char*)d_ws;
    float* e2   = (float*)(ws);                              // 32 KB
    float* z2   = (float*)(ws + 32 * 1024);                  // 64 KB
    int*   idxb = (int*)  (ws + 96 * 1024);                  // 64 KB
    float* loss = (float*)(ws + 160 * 1024);                 // 4 B
    float* s_in = loss + 1;                                  // 4 B

    convert_z_kernel<<<4096, 256, 0, stream>>>(z, zhi, zlo);
    convert_e_kernel<<<2048, 256, 0, stream>>>(E, ehi, elo);
    norms_np_kernel<<<K_CODES / 8, 256, 0, stream>>>(E, e2);
    norms_np_kernel<<<N_ROWS / 8, 256, 0, stream>>>(z, z2);
    argmin_mfma_kernel<<<NRB * NCB, 512, 0, stream>>>(zhi, zlo, ehi, elo, e2, z2, pv, pi);
    combine_kernel<<<N_ROWS / 256, 256, 0, stream>>>(pv, pi, idxb, out2);

    // zero accumulators (after out5 scratch is consumed; harness doesn't re-poison)
    hipMemsetAsync(out4, 0, K_CODES * sizeof(float), stream);
    hipMemsetAsync(out5, 0, (size_t)K_CODES * D_DIM * sizeof(float), stream);
    hipMemsetAsync(loss, 0, sizeof(float), stream);

    gather_kernel<<<N_ROWS, 128, 0, stream>>>(z, E, idxb, out0, out4, out5, loss);
    sum_cs_kernel<<<1, 256, 0, stream>>>(in_cs, s_in);
    finalize_kernel<<<K_CODES, 128, 0, stream>>>(in_cs, in_es, out1, out3, out4, out5, s_in, loss);
}

// Round 7
// 747.600 us; speedup vs baseline: 1.3843x; 1.3843x over previous
//
#include <hip/hip_runtime.h>
#include <hip/hip_bf16.h>
#include <math.h>

#define K_CODES 8192
#define D_DIM   512
#define N_ROWS  16384
#define DECAYF  0.99f
#define OMDF    0.01f
#define COMMIT  0.25f
#define EPSV    1e-5f

// output offsets (in floats), reference return order:
// z_q_st (8*2048*512), loss (1), indices (8*2048), new_embedding (8192*512),
// ema_cs (8192), ema_es (8192*512)
#define OUT0_OFF 0ull
#define OUT1_OFF 8388608ull
#define OUT2_OFF 8388609ull
#define OUT3_OFF 8404993ull
#define OUT4_OFF 12599297ull
#define OUT5_OFF 12607489ull

#define BM 256
#define BN 256
#define BKC 32
#define NRB (N_ROWS / BM)    // 64 rowblocks
#define NCB (K_CODES / BN)   // 32 colblocks
#define NITER (D_DIM / BKC)  // 16

typedef _Float16 f16x8 __attribute__((ext_vector_type(8)));
typedef float    f32x4 __attribute__((ext_vector_type(4)));
typedef unsigned short u16;

#define GLOAD16(srcp, dstp) __builtin_amdgcn_global_load_lds( \
    (const __attribute__((address_space(1))) unsigned int*)(const void*)(srcp), \
    (__attribute__((address_space(3))) unsigned int*)(void*)(dstp), 16, 0, 0)

// ---------------- exact numpy pairwise sum of squares, wave-parallel ----------------
// numpy pairwise(512) = ((B0+B1)+(B2+B3)), each B = base-128 block:
// r[j] = p[j]; r[j] += p[8i+j] for i=1..15; ((r0+r1)+(r2+r3))+((r4+r5)+(r6+r7)).
// Lane j of an 8-lane group owns r[j]; IEEE RN add is commutative, so the
// shfl_xor tree reproduces numpy's exact pairing.
__global__ void norms_np_kernel(const float* __restrict__ src, float* __restrict__ dst) {
    int lane = threadIdx.x & 63;
    int wave = threadIdx.x >> 6;            // 4 waves/block
    int half = lane >> 5;                   // row within wave (2 rows/wave)
    int l32  = lane & 31;
    int row  = blockIdx.x * 8 + wave * 2 + half;
    int j    = l32 & 7;
    int blk  = l32 >> 3;
    const float* p = src + (size_t)row * D_DIM + blk * 128 + j;
    float x0 = p[0];
    float r = __fmul_rn(x0, x0);
#pragma unroll
    for (int i = 1; i < 16; i++) {
        float x = p[i * 8];
        r = __fadd_rn(r, __fmul_rn(x, x));
    }
    float s1 = __fadd_rn(r,  __shfl_xor(r, 1, 64));
    float s2 = __fadd_rn(s1, __shfl_xor(s1, 2, 64));
    float s4 = __fadd_rn(s2, __shfl_xor(s2, 4, 64));   // B[blk]
    float t1 = __fadd_rn(s4, __shfl_xor(s4, 8, 64));   // B0+B1 | B2+B3
    float t2 = __fadd_rn(t1, __shfl_xor(t1, 16, 64));  // total
    if (l32 == 0) dst[row] = t2;
}

// ---------------- hi/lo fp16 split + chunk-pack converters ----------------
// Packed layout (16B granules): pack[((blk*16 + t)*2 + plane)*1024 + slot],
// slot = g*256 + r, holding src[blk*256 + r][t*32 + g*8 .. +7] as f16 —
// byte-identical to the LDS image the GEMM stages, so staging reads are
// fully contiguous 1KB-per-wave streams.
__global__ void pack_z_kernel(const float* __restrict__ z, u16* __restrict__ zpack) {
    int gid = blockIdx.x * 256 + threadIdx.x;   // 16384 rows * 64 q
    int row = gid >> 6, q = gid & 63;
    int t = q >> 2, g = q & 3;
    int rb = row >> 8, r = row & 255;
    const float4* src = (const float4*)(z + (size_t)row * D_DIM + q * 8);
    float4 v0 = src[0], v1 = src[1];
    float vv[8] = {v0.x, v0.y, v0.z, v0.w, v1.x, v1.y, v1.z, v1.w};
    f16x8 hv, lv;
#pragma unroll
    for (int j = 0; j < 8; j++) {
        _Float16 h = (_Float16)vv[j];
        hv[j] = h;
        lv[j] = (_Float16)(vv[j] - (float)h);
    }
    size_t base = (((size_t)rb * 16 + t) * 2) * 1024 + g * 256 + r;
    ((f16x8*)zpack)[base] = hv;
    ((f16x8*)zpack)[base + 1024] = lv;
}

__global__ void pack_e_kernel(const float* __restrict__ E, u16* __restrict__ epack) {
    int gid = blockIdx.x * 256 + threadIdx.x;   // 8192 rows * 64 q
    int row = gid >> 6, q = gid & 63;
    int t = q >> 2, g = q & 3;
    int cb = row >> 8, r = row & 255;
    const float4* src = (const float4*)(E + (size_t)row * D_DIM + q * 8);
    float4 v0 = src[0], v1 = src[1];
    float vv[8] = {v0.x, v0.y, v0.z, v0.w, v1.x, v1.y, v1.z, v1.w};
    f16x8 hv, lv;
#pragma unroll
    for (int j = 0; j < 8; j++) {
        float s = vv[j] * 4096.0f;     // exact exponent shift
        _Float16 h = (_Float16)s;
        hv[j] = h;
        lv[j] = (_Float16)(s - (float)h);
    }
    size_t base = (((size_t)cb * 16 + t) * 2) * 1024 + g * 256 + r;
    ((f16x8*)epack)[base] = hv;
    ((f16x8*)epack)[base + 1024] = lv;
}

// ---------------- MFMA distance GEMM + argmin (packed streaming staging) ----------
// dist = fl( fl(z2 - acc*2^-11) + e2 ), acc = 3-product split dot * 4096.
// Identical schedule/numerics to the r3 kernel; only the staging sources are
// the chunk-packed arrays (contiguous 16KB streams per plane per chunk).
__global__ __launch_bounds__(512, 1) void argmin_mfma_kernel(
    const u16* __restrict__ zpack, const u16* __restrict__ epack,
    const float* __restrict__ e2, const float* __restrict__ z2,
    float* __restrict__ pv, int* __restrict__ pi)
{
    // [buf][plane: Ah,Al,Bh,Bl][slot: g*256 + r][8 f16] = 128 KB
    __shared__ __align__(16) u16 lds[2][4][1024][8];

    int bid = blockIdx.x;
    int xcd = bid & 7, sub = bid >> 3;       // 2048 = 8 XCDs * 256
    int nb  = xcd * 256 + sub;
    int cb  = nb >> 6;                       // each XCD owns 4 colblocks
    int rb  = nb & 63;
    int row0 = rb * BM, col0 = cb * BN;

    int tid = threadIdx.x;
    int l   = tid & 63;
    int w   = tid >> 6;
    int mw  = w >> 2, nw = w & 3;            // wave grid 2(m) x 4(n), 128x64 per wave
    int lg  = l >> 4;                        // k-group 0..3
    int l16 = l & 15;

    f32x4 acc[8][4];
#pragma unroll
    for (int m = 0; m < 8; m++)
#pragma unroll
        for (int n = 0; n < 4; n++)
            acc[m][n] = (f32x4){0.f, 0.f, 0.f, 0.f};

    auto stage_all = [&](int buf, int t) {
        const u16* zb = zpack + (((size_t)rb * 16 + t) * 2) * 8192;  // plane = 8192 u16
        const u16* eb = epack + (((size_t)cb * 16 + t) * 2) * 8192;
#pragma unroll
        for (int i = 0; i < 2; i++) {
            int slot = tid + i * 512;
            GLOAD16(zb + (size_t)slot * 8,        &lds[buf][0][slot][0]);
            GLOAD16(zb + 8192 + (size_t)slot * 8, &lds[buf][1][slot][0]);
            GLOAD16(eb + (size_t)slot * 8,        &lds[buf][2][slot][0]);
            GLOAD16(eb + 8192 + (size_t)slot * 8, &lds[buf][3][slot][0]);
        }
    };

    stage_all(0, 0);
    __syncthreads();   // drains vmcnt before barrier
    int cur = 0;
    for (int t = 0; t < NITER; t++) {
        if (t < NITER - 1) stage_all(cur ^ 1, t + 1);
        f16x8 bh[4], bl[4];
#pragma unroll
        for (int n = 0; n < 4; n++) {
            int s = lg * 256 + nw * 64 + n * 16 + l16;
            bh[n] = *(const f16x8*)&lds[cur][2][s][0];
            bl[n] = *(const f16x8*)&lds[cur][3][s][0];
        }
#pragma unroll
        for (int m = 0; m < 8; m++) {
            int s = lg * 256 + mw * 128 + m * 16 + l16;
            f16x8 ah = *(const f16x8*)&lds[cur][0][s][0];
            f16x8 al = *(const f16x8*)&lds[cur][1][s][0];
#pragma unroll
            for (int n = 0; n < 4; n++)
                acc[m][n] = __builtin_amdgcn_mfma_f32_16x16x32_f16(ah, bh[n], acc[m][n], 0, 0, 0);
#pragma unroll
            for (int n = 0; n < 4; n++)
                acc[m][n] = __builtin_amdgcn_mfma_f32_16x16x32_f16(ah, bl[n], acc[m][n], 0, 0, 0);
#pragma unroll
            for (int n = 0; n < 4; n++)
                acc[m][n] = __builtin_amdgcn_mfma_f32_16x16x32_f16(al, bh[n], acc[m][n], 0, 0, 0);
        }
        __syncthreads();   // drains vmcnt+lgkmcnt, protects both buffers
        cur ^= 1;
    }

    // ---- epilogue: distances + first-occurrence argmin ----
    const float nscale = -0.00048828125f;   // -2^-11 (undo 4096 scale, apply -2)
    float e2c[4];
#pragma unroll
    for (int n = 0; n < 4; n++) e2c[n] = e2[col0 + nw * 64 + n * 16 + l16];

    float* redv = (float*)&lds[0][0][0][0];       // [256][4] vals  (4 KB)
    int*   redi = (int*)((char*)redv + 4096);     // [256][4] idx   (4 KB)

#pragma unroll
    for (int m = 0; m < 8; m++) {
#pragma unroll
        for (int r = 0; r < 4; r++) {
            int rl = mw * 128 + m * 16 + lg * 4 + r;
            float z2v = z2[row0 + rl];
            float bv = 1e30f; int bc = 0x7fffffff;
#pragma unroll
            for (int n = 0; n < 4; n++) {
                int code = col0 + nw * 64 + n * 16 + l16;
                float v = __fadd_rn(__fadd_rn(z2v, __fmul_rn(acc[m][n][r], nscale)), e2c[n]);
                if (v < bv) { bv = v; bc = code; }   // n ascending => code ascending
            }
#pragma unroll
            for (int s = 1; s < 16; s <<= 1) {
                float ov = __shfl_xor(bv, s, 64);
                int   oc = __shfl_xor(bc, s, 64);
                if (ov < bv || (ov == bv && oc < bc)) { bv = ov; bc = oc; }
            }
            if (l16 == r) {
                redv[rl * 4 + nw] = bv;
                redi[rl * 4 + nw] = bc;
            }
        }
    }
    __syncthreads();
    if (tid < BM) {
        float bv = redv[tid * 4]; int bc = redi[tid * 4];
#pragma unroll
        for (int q = 1; q < 4; q++) {
            float v = redv[tid * 4 + q]; int c = redi[tid * 4 + q];
            if (v < bv || (v == bv && c < bc)) { bv = v; bc = c; }
        }
        pv[(size_t)cb * N_ROWS + row0 + tid] = bv;
        pi[(size_t)cb * N_ROWS + row0 + tid] = bc;
    }
}

// ---------------- combine colblock partials -> final index ----------------
__global__ void combine_kernel(const float* __restrict__ pv, const int* __restrict__ pi,
                               int* __restrict__ idx_out, float* __restrict__ out2) {
    int row = blockIdx.x * 256 + threadIdx.x;
    float bv = pv[row];
    int   bi = pi[row];
#pragma unroll 4
    for (int cb = 1; cb < NCB; cb++) {
        float v = pv[(size_t)cb * N_ROWS + row];
        int   c = pi[(size_t)cb * N_ROWS + row];
        if (v < bv || (v == bv && c < bi)) { bv = v; bi = c; }
    }
    idx_out[row] = bi;
    out2[row] = (float)bi;
}

// ---------------- gather z_q, loss, segment-sum scatter ----------------
__global__ void gather_kernel(const float* __restrict__ z, const float* __restrict__ E,
                              const int* __restrict__ idx, float* __restrict__ out0,
                              float* __restrict__ out4_acc, float* __restrict__ out5_acc,
                              float* __restrict__ loss_acc) {
    int row = blockIdx.x;
    int t = threadIdx.x;   // 128
    int k = idx[row];
    int d = t * 4;
    float4 zv = *(const float4*)(z + (size_t)row * D_DIM + d);
    float4 qv = *(const float4*)(E + (size_t)k * D_DIM + d);
    float4 o;
    o.x = __fadd_rn(zv.x, __fsub_rn(qv.x, zv.x));
    o.y = __fadd_rn(zv.y, __fsub_rn(qv.y, zv.y));
    o.z = __fadd_rn(zv.z, __fsub_rn(qv.z, zv.z));
    o.w = __fadd_rn(zv.w, __fsub_rn(qv.w, zv.w));
    *(float4*)(out0 + (size_t)row * D_DIM + d) = o;
    float dx = qv.x - zv.x, dy = qv.y - zv.y, dz = qv.z - zv.z, dw = qv.w - zv.w;
    float s = dx * dx + dy * dy + dz * dz + dw * dw;
#pragma unroll
    for (int off = 32; off; off >>= 1) s += __shfl_down(s, off, 64);
    __shared__ float part[2];
    if ((t & 63) == 0) part[t >> 6] = s;
    __syncthreads();
    if (t == 0) atomicAdd(loss_acc, part[0] + part[1]);
    float* dst = out5_acc + (size_t)k * D_DIM + d;
    atomicAdd(dst + 0, OMDF * zv.x);
    atomicAdd(dst + 1, OMDF * zv.y);
    atomicAdd(dst + 2, OMDF * zv.z);
    atomicAdd(dst + 3, OMDF * zv.w);
    if (t == 0) atomicAdd(out4_acc + k, OMDF);
}

// ---------------- sum of input ema_cluster_size ----------------
__global__ void sum_cs_kernel(const float* __restrict__ cs, float* __restrict__ out_sum) {
    int t = threadIdx.x;  // 256
    float s = 0.f;
    for (int i = t; i < K_CODES; i += 256) s += cs[i];
#pragma unroll
    for (int off = 32; off; off >>= 1) s += __shfl_down(s, off, 64);
    __shared__ float part[4];
    if ((t & 63) == 0) part[t >> 6] = s;
    __syncthreads();
    if (t == 0) out_sum[0] = part[0] + part[1] + part[2] + part[3];
}

// ---------------- EMA finalize + smoothing + new embedding ----------------
__global__ void finalize_kernel(const float* __restrict__ in_cs, const float* __restrict__ in_es,
                                float* __restrict__ out1, float* __restrict__ out3,
                                float* __restrict__ out4, float* __restrict__ out5,
                                const float* __restrict__ s_in, const float* __restrict__ loss_acc) {
    int k = blockIdx.x;
    int t = threadIdx.x;  // 128
    float cs_acc = out4[k];                       // 0.01 * count_k (accumulated)
    float ema_cs = DECAYF * in_cs[k] + cs_acc;
    float n = DECAYF * s_in[0] + OMDF * (float)N_ROWS;
    float smoothed = (ema_cs + EPSV) / (n + (float)K_CODES * EPSV) * n;
    int d = t * 4;
    float4 esv = *(const float4*)(in_es + (size_t)k * D_DIM + d);
    float4 accv = *(const float4*)(out5 + (size_t)k * D_DIM + d);
    float4 ema;
    ema.x = DECAYF * esv.x + accv.x;
    ema.y = DECAYF * esv.y + accv.y;
    ema.z = DECAYF * esv.z + accv.z;
    ema.w = DECAYF * esv.w + accv.w;
    *(float4*)(out5 + (size_t)k * D_DIM + d) = ema;
    float4 emb;
    emb.x = ema.x / smoothed;
    emb.y = ema.y / smoothed;
    emb.z = ema.z / smoothed;
    emb.w = ema.w / smoothed;
    *(float4*)(out3 + (size_t)k * D_DIM + d) = emb;
    if (t == 0) out4[k] = ema_cs;
    if (k == 0 && t == 0) out1[0] = COMMIT * loss_acc[0] / (float)(N_ROWS * D_DIM);
}

extern "C" void kernel_launch(void* const* d_in, const int* in_sizes, int n_in,
                              void* d_out, int out_size, void* d_ws, size_t ws_size,
                              hipStream_t stream) {
    const float* z     = (const float*)d_in[0];
    const float* E     = (const float*)d_in[1];
    const float* in_cs = (const float*)d_in[2];
    const float* in_es = (const float*)d_in[3];

    float* out  = (float*)d_out;
    float* out0 = out + OUT0_OFF;
    float* out1 = out + OUT1_OFF;
    float* out2 = out + OUT2_OFF;
    float* out3 = out + OUT3_OFF;
    float* out4 = out + OUT4_OFF;
    float* out5 = out + OUT5_OFF;

    // chunk-packed hi/lo fp16 planes stashed in output regions (overwritten later):
    u16* zpack = (u16*)out0;                                 // 32 MB = out0 exactly
    u16* epack = (u16*)(out + OUT3_OFF + 3);                 // 16 MB, 16B-aligned; spills 3 floats into out4 (memset later)
    // argmin partials scratch in out5 region (memset happens after combine):
    float* pv = out5;                                        // 32*16384 floats = 2 MB
    int*   pi = (int*)(out5 + (size_t)NCB * N_ROWS);         // 2 MB

    char* ws = (char*)d_ws;
    float* e2   = (float*)(ws);                              // 32 KB
    float* z2   = (float*)(ws + 32 * 1024);                  // 64 KB
    int*   idxb = (int*)  (ws + 96 * 1024);                  // 64 KB
    float* loss = (float*)(ws + 160 * 1024);                 // 4 B
    float* s_in = loss + 1;                                  // 4 B

    pack_z_kernel<<<4096, 256, 0, stream>>>(z, zpack);
    pack_e_kernel<<<2048, 256, 0, stream>>>(E, epack);
    norms_np_kernel<<<K_CODES / 8, 256, 0, stream>>>(E, e2);
    norms_np_kernel<<<N_ROWS / 8, 256, 0, stream>>>(z, z2);
    argmin_mfma_kernel<<<NRB * NCB, 512, 0, stream>>>(zpack, epack, e2, z2, pv, pi);
    combine_kernel<<<N_ROWS / 256, 256, 0, stream>>>(pv, pi, idxb, out2);

    // zero accumulators (after out5 scratch is consumed; harness doesn't re-poison)
    hipMemsetAsync(out4, 0, K_CODES * sizeof(float), stream);
    hipMemsetAsync(out5, 0, (size_t)K_CODES * D_DIM * sizeof(float), stream);
    hipMemsetAsync(loss, 0, sizeof(float), stream);

    gather_kernel<<<N_ROWS, 128, 0, stream>>>(z, E, idxb, out0, out4, out5, loss);
    sum_cs_kernel<<<1, 256, 0, stream>>>(in_cs, s_in);
    finalize_kernel<<<K_CODES, 128, 0, stream>>>(in_cs, in_es, out1, out3, out4, out5, s_in, loss);
}